// Round 2
// baseline (389.987 us; speedup 1.0000x reference)
//
#include <hip/hip_runtime.h>
#include <hip/hip_fp16.h>

#define NN 100000
#define NE 3200000
#define NG 128
#define BN_EPS 1e-5f

#define NBUK 782          // ceil(100000 / 128)
#define BSHIFT 7          // bucket = dst >> 7 (128 nodes per bucket)
#define BCAP 6144         // slab capacity per bucket (mean 4096, +32 sigma)

#define GRID_SG 1024      // persistent blocks, 4/CU
#define PBMAX 2048        // partial-buffer column stride
#define PSLICE 8          // pool slices per graph

typedef _Float16 h2v __attribute__((ext_vector_type(2)));
typedef unsigned int u32x2 __attribute__((ext_vector_type(2)));
typedef unsigned int u32x4 __attribute__((ext_vector_type(4)));

static __device__ __forceinline__ h2v as_h2(unsigned int u) {
    return __builtin_bit_cast(h2v, u);
}
static __device__ __forceinline__ unsigned int as_u32(h2v h) {
    return __builtin_bit_cast(unsigned int, h);
}

// Lessons ledger:
// r9: no grid-wide spin barriers. r10: no device fences in gather kernels.
// r12: nt only full-line write-once / read-once streams.
// r13: nt-data consumers need block parallelism.
// r14: FETCH == L2-miss traffic; table at ~60% L2-hit equilibrium.
// r15/r17: BN-in-gather VALU cost -> packed fp16; r18 pair-accumulates.
// r19 FAILED: LDS-staged indices + 16-burst neutral (87µs both ways);
//      gather latency is NOT the binding resource. VGPR stayed 32.
// r20 (this round): theory = GEMM phase is DS-INSTRUCTION-bound (320
//      ds_read_b32/tile/wave ~ 60µs/CU of LDS pipe, no counter shows it).
//      Fix: b128 LDS reads (4x fewer DS instrs) + BN pre-applied once per
//      node (k_bnact) instead of per-edge (32x redundant VALU).

// ---------------- bucketed edge scatter (counting-sort level 1) ----------------
__global__ void __launch_bounds__(512) k_scatter(
    const int* __restrict__ src, const int* __restrict__ dst,
    int* __restrict__ slab_cursor, unsigned int* __restrict__ slab, int E) {
    __shared__ int hist[NBUK + 2];
    __shared__ int cbase[NBUK + 2];
    int tid = threadIdx.x;
    int eBeg = blockIdx.x * 12500;
    int eEnd = min(eBeg + 12500, E);

    for (int t = tid; t < NBUK; t += 512) hist[t] = 0;
    __syncthreads();
    for (int e = eBeg + tid; e < eEnd; e += 512) {
        int b = dst[e] >> BSHIFT;
        atomicAdd(&hist[b], 1);
    }
    __syncthreads();
    for (int t = tid; t < NBUK; t += 512) {
        int c = hist[t];
        cbase[t] = (c > 0) ? atomicAdd(&slab_cursor[t], c) : 0;
    }
    __syncthreads();
    for (int t = tid; t < NBUK; t += 512) hist[t] = 0;
    __syncthreads();
    for (int e = eBeg + tid; e < eEnd; e += 512) {
        int d = dst[e];
        int b = d >> BSHIFT;
        int r = atomicAdd(&hist[b], 1);
        int pos = cbase[b] + r;
        if (pos < BCAP) slab[(size_t)b * BCAP + pos] = ((unsigned)src[e] << BSHIFT) | (unsigned)(d & 127);
    }
}

// ---------------- per-bucket CSR build + FUSED LAYER 1 (scan folded in) ----------------
__global__ void __launch_bounds__(512) k_bucket_csr(
    const unsigned int* __restrict__ slab, const int* __restrict__ slab_cursor,
    int* __restrict__ row_ptr,
    float* __restrict__ deg_inv, int* __restrict__ csr_src,
    const float* __restrict__ x, const float* __restrict__ w1l,
    const float* __restrict__ b1, const float* __restrict__ w1r,
    __half* __restrict__ hp16, float* __restrict__ part) {
    __shared__ int lds_csr[BCAP];
    __shared__ int red[512];
    __shared__ int sdeg[128];
    __shared__ int sscan[128];
    __shared__ int slcur[128];
    __shared__ float swl[256], swr[256], sb1[64];
    __shared__ float ssum[64], ssq[64];
    int tid = threadIdx.x;
    int b = blockIdx.x;
    int lo = b << BSHIFT;
    int cnt = min(slab_cursor[b], BCAP);
    const unsigned int* sl = slab + (size_t)b * BCAP;

    // inline exclusive prefix over bucket counts
    int partial = 0;
    for (int j = tid; j < b; j += 512) partial += min(slab_cursor[j], BCAP);
    red[tid] = partial;
    __syncthreads();
    for (int off = 256; off > 0; off >>= 1) {
        if (tid < off) red[tid] += red[tid + off];
        __syncthreads();
    }
    int base = red[0];
    if (b == NBUK - 1 && tid == 0) row_ptr[NN] = base + cnt;

    if (tid < 256) { swl[tid] = w1l[tid]; swr[tid] = w1r[tid]; }
    if (tid < 64)  { sb1[tid] = b1[tid]; ssum[tid] = 0.f; ssq[tid] = 0.f; }
    if (tid < 128) sdeg[tid] = 0;
    __syncthreads();

    // single global pass: stage slab entries in registers
    unsigned int myv[12];
    int mycount = 0;
    for (int k = tid; k < cnt; k += 512) myv[mycount++] = sl[k];
#pragma unroll
    for (int j = 0; j < 12; j++)
        if (j < mycount) atomicAdd(&sdeg[myv[j] & 127], 1);
    __syncthreads();
    int v = (tid < 128) ? sdeg[tid] : 0;
    if (tid < 128) sscan[tid] = v;
    __syncthreads();
    for (int off = 1; off < 128; off <<= 1) {
        int add = 0;
        if (tid < 128 && tid >= off) add = sscan[tid - off];
        __syncthreads();
        if (tid < 128) sscan[tid] += add;
        __syncthreads();
    }
    if (tid < 128) {
        int excl = sscan[tid] - v;
        int n = lo + tid;
        if (n < NN) {
            row_ptr[n] = base + excl;
            deg_inv[n] = 1.0f / fmaxf((float)v, 1.0f);
        }
        slcur[tid] = excl;   // LOCAL cursor
    }
    __syncthreads();
#pragma unroll
    for (int j = 0; j < 12; j++)
        if (j < mycount) {
            unsigned int p = myv[j];
            int pos = atomicAdd(&slcur[p & 127], 1);
            lds_csr[pos] = (int)(p >> BSHIFT);
        }
    __syncthreads();
    // cached store: csr_src re-read by both k_sage layers
    for (int k = tid; k < cnt; k += 512) csr_src[base + k] = lds_csr[k];

    // ---- Phase B: layer 1 (x-gather 4-deep pipelined) ----
    int i = tid >> 2, c = tid & 3;
    int n = lo + i;
    bool valid = (n < NN);
    int dhi = sscan[i];
    int dlo = dhi - sdeg[i];
    const float4* x4 = (const float4*)x;
    float4 acc = make_float4(0.f, 0.f, 0.f, 0.f);
    int k = dlo + c;
    for (; k + 12 < dhi; k += 16) {
        int s0 = lds_csr[k], s1 = lds_csr[k + 4], s2 = lds_csr[k + 8], s3 = lds_csr[k + 12];
        float4 v0 = x4[s0];
        float4 v1 = x4[s1];
        float4 v2 = x4[s2];
        float4 v3 = x4[s3];
        acc.x += v0.x + v1.x + v2.x + v3.x;
        acc.y += v0.y + v1.y + v2.y + v3.y;
        acc.z += v0.z + v1.z + v2.z + v3.z;
        acc.w += v0.w + v1.w + v2.w + v3.w;
    }
    for (; k < dhi; k += 4) {
        int s = lds_csr[k];
        float4 xv = x4[s];
        acc.x += xv.x; acc.y += xv.y; acc.z += xv.z; acc.w += xv.w;
    }
#pragma unroll
    for (int m = 1; m <= 2; m <<= 1) {
        acc.x += __shfl_xor(acc.x, m);
        acc.y += __shfl_xor(acc.y, m);
        acc.z += __shfl_xor(acc.z, m);
        acc.w += __shfl_xor(acc.w, m);
    }
    float dv = 1.0f / fmaxf((float)sdeg[i], 1.0f);
    float ax = acc.x * dv, ay = acc.y * dv, az = acc.z * dv, aw = acc.w * dv;
    float4 xs = valid ? x4[n] : make_float4(0.f, 0.f, 0.f, 0.f);

#pragma unroll
    for (int m4 = 0; m4 < 4; m4++) {
        float4 o = make_float4(0.f, 0.f, 0.f, 0.f);
        float* op = &o.x;
        if (valid) {
#pragma unroll
            for (int t = 0; t < 4; t++) {
                int j = c * 16 + m4 * 4 + t;
                float s = sb1[j];
                s += ax * swl[j * 4 + 0] + ay * swl[j * 4 + 1] + az * swl[j * 4 + 2] + aw * swl[j * 4 + 3];
                s += xs.x * swr[j * 4 + 0] + xs.y * swr[j * 4 + 1] + xs.z * swr[j * 4 + 2] + xs.w * swr[j * 4 + 3];
                op[t] = s;
            }
            h2v p0 = h2v{(_Float16)o.x, (_Float16)o.y};
            h2v p1 = h2v{(_Float16)o.z, (_Float16)o.w};
            u32x2 w;
            w.x = *(unsigned int*)&p0;
            w.y = *(unsigned int*)&p1;
            __builtin_nontemporal_store(w, (u32x2*)hp16 + (size_t)n * 16 + c * 4 + m4);
        }
        float4 q = make_float4(o.x * o.x, o.y * o.y, o.z * o.z, o.w * o.w);
#pragma unroll
        for (int m = 4; m <= 32; m <<= 1) {
            o.x += __shfl_xor(o.x, m); o.y += __shfl_xor(o.y, m);
            o.z += __shfl_xor(o.z, m); o.w += __shfl_xor(o.w, m);
            q.x += __shfl_xor(q.x, m); q.y += __shfl_xor(q.y, m);
            q.z += __shfl_xor(q.z, m); q.w += __shfl_xor(q.w, m);
        }
        if ((tid & 63) < 4) {
            int jb = c * 16 + m4 * 4;
            atomicAdd(&ssum[jb + 0], o.x); atomicAdd(&ssum[jb + 1], o.y);
            atomicAdd(&ssum[jb + 2], o.z); atomicAdd(&ssum[jb + 3], o.w);
            atomicAdd(&ssq[jb + 0], q.x);  atomicAdd(&ssq[jb + 1], q.y);
            atomicAdd(&ssq[jb + 2], q.z);  atomicAdd(&ssq[jb + 3], q.w);
        }
    }
    __syncthreads();
    if (tid < 64) {
        part[(2 * tid) * PBMAX + blockIdx.x]     = ssum[tid];
        part[(2 * tid + 1) * PBMAX + blockIdx.x] = ssq[tid];
    }
}

// ---------------- BN+ReLU applied ONCE per node (r20) ----------------
// hp (pre-BN fp16) -> ha (activated fp16). 25.6 MB streaming, ~4.3 us.
__global__ void __launch_bounds__(256) k_bnact(
    const __half* __restrict__ hp, const float* __restrict__ sbv,
    __half* __restrict__ ha) {
    __shared__ float s_sc[64], s_bi[64];
    int tid = threadIdx.x;
    if (tid < 64) { s_sc[tid] = sbv[tid]; s_bi[tid] = sbv[64 + tid]; }
    __syncthreads();
    int c = tid & 7;   // covers fp16 channels 8c..8c+7 (stride keeps i&7 == tid&7)
    h2v sc[4], bi[4];
#pragma unroll
    for (int j = 0; j < 4; j++) {
        sc[j] = h2v{(_Float16)s_sc[8 * c + 2 * j], (_Float16)s_sc[8 * c + 2 * j + 1]};
        bi[j] = h2v{(_Float16)s_bi[8 * c + 2 * j], (_Float16)s_bi[8 * c + 2 * j + 1]};
    }
    h2v hz = h2v{(_Float16)0.f, (_Float16)0.f};
    const u32x4* in4 = (const u32x4*)hp;
    u32x4* out4 = (u32x4*)ha;
    const int total = NN * 8;   // u32x4 elements
    for (int i = blockIdx.x * 256 + tid; i < total; i += gridDim.x * 256) {
        u32x4 v = in4[i];
#pragma unroll
        for (int j = 0; j < 4; j++) {
            h2v a = as_h2(v[j]);
            a = __builtin_elementwise_max(a * sc[j] + bi[j], hz);
            v[j] = as_u32(a);
        }
        out4[i] = v;
    }
}

// ---------------- fused SAGE layer: pure fp16 gather-sum + b128-fed GEMM ----------------
// r20: input is pre-activated (k_bnact), gather is pure pair-adds; GEMM phase
//      reads weights/tA/tX as ds_read_b128 (80 DS instrs/tile/wave vs 320).
__global__ void __launch_bounds__(512, 8) k_sage(
    const __half* __restrict__ h_act,
    const int* __restrict__ row_ptr,
    const int* __restrict__ csr_src, const float* __restrict__ deg_inv,
    const float* __restrict__ wl, const float* __restrict__ bl,
    const float* __restrict__ wr, __half* __restrict__ hp16,
    float* __restrict__ part) {
    __shared__ h2v wl2s[32][68];   // [k-pair][out-channel]; row stride 272B (16-aligned)
    __shared__ h2v wr2s[32][68];
    __shared__ h2v tAh[32][36];    // row stride 144B (16-aligned)
    __shared__ h2v tXh[32][36];
    __shared__ float ssum[64], ssq[64];
    int tid = threadIdx.x;
    for (int idx = tid; idx < 2048; idx += 512) {
        int j = idx & 63, kk = idx >> 6;
        float2 l = ((const float2*)wl)[j * 32 + kk];
        float2 r = ((const float2*)wr)[j * 32 + kk];
        wl2s[kk][j] = h2v{(_Float16)l.x, (_Float16)l.y};
        wr2s[kk][j] = h2v{(_Float16)r.x, (_Float16)r.y};
    }
    if (tid < 64) { ssum[tid] = 0.f; ssq[tid] = 0.f; }
    __syncthreads();

    int g = tid & 15, ni = tid >> 4;      // ni in [0,32)
    unsigned g8 = (unsigned)(g << 3);
    h2v hz = h2v{(_Float16)0.f, (_Float16)0.f};
    const char* hb = (const char*)h_act;
    const int ntiles = NN / 32;           // 3125 exactly
    float4 bo = ((const float4*)bl)[g];   // bias hoisted out of tile loop

    for (int tile = blockIdx.x; tile < ntiles; tile += GRID_SG) {
        int n = (tile << 5) + ni;
        int r0 = row_ptr[n], r1 = row_ptr[n + 1];
        float di = deg_inv[n];
        // self row: issue early, independent of edge loop
        uint2 rsv = *(const uint2*)(hb + (((unsigned)n << 7) | g8));
        float ax = 0.f, ay = 0.f, az = 0.f, aw = 0.f;
        int e = r0;
        for (; e + 8 <= r1; e += 8) {
            int s0 = csr_src[e],     s1 = csr_src[e + 1], s2 = csr_src[e + 2], s3 = csr_src[e + 3];
            int s4 = csr_src[e + 4], s5 = csr_src[e + 5], s6 = csr_src[e + 6], s7 = csr_src[e + 7];
            uint2 v0 = *(const uint2*)(hb + (((unsigned)s0 << 7) | g8));
            uint2 v1 = *(const uint2*)(hb + (((unsigned)s1 << 7) | g8));
            uint2 v2 = *(const uint2*)(hb + (((unsigned)s2 << 7) | g8));
            uint2 v3 = *(const uint2*)(hb + (((unsigned)s3 << 7) | g8));
            uint2 v4 = *(const uint2*)(hb + (((unsigned)s4 << 7) | g8));
            uint2 v5 = *(const uint2*)(hb + (((unsigned)s5 << 7) | g8));
            uint2 v6 = *(const uint2*)(hb + (((unsigned)s6 << 7) | g8));
            uint2 v7 = *(const uint2*)(hb + (((unsigned)s7 << 7) | g8));
            h2v hacc0 = hz, hacc1 = hz;
            hacc0 += as_h2(v0.x); hacc1 += as_h2(v0.y);
            hacc0 += as_h2(v1.x); hacc1 += as_h2(v1.y);
            hacc0 += as_h2(v2.x); hacc1 += as_h2(v2.y);
            hacc0 += as_h2(v3.x); hacc1 += as_h2(v3.y);
            hacc0 += as_h2(v4.x); hacc1 += as_h2(v4.y);
            hacc0 += as_h2(v5.x); hacc1 += as_h2(v5.y);
            hacc0 += as_h2(v6.x); hacc1 += as_h2(v6.y);
            hacc0 += as_h2(v7.x); hacc1 += as_h2(v7.y);
            ax += (float)hacc0.x; ay += (float)hacc0.y;
            az += (float)hacc1.x; aw += (float)hacc1.y;
        }
        for (; e < r1; ++e) {
            int s = csr_src[e];
            uint2 vv = *(const uint2*)(hb + (((unsigned)s << 7) | g8));
            h2v a0 = as_h2(vv.x), a1 = as_h2(vv.y);
            ax += (float)a0.x; ay += (float)a0.y; az += (float)a1.x; aw += (float)a1.y;
        }
        ax *= di; ay *= di; az *= di; aw *= di;
        tAh[ni][2 * g]     = h2v{(_Float16)ax, (_Float16)ay};
        tAh[ni][2 * g + 1] = h2v{(_Float16)az, (_Float16)aw};
        tXh[ni][2 * g]     = as_h2(rsv.x);
        tXh[ni][2 * g + 1] = as_h2(rsv.y);
        __syncthreads();

        float4 o = bo;
#pragma unroll
        for (int kk = 0; kk < 32; kk += 4) {
            u32x4 av = *(const u32x4*)&tAh[ni][kk];
            u32x4 xv = *(const u32x4*)&tXh[ni][kk];
#pragma unroll
            for (int j = 0; j < 4; j++) {
                u32x4 wlv = *(const u32x4*)&wl2s[kk + j][4 * g];
                u32x4 wrv = *(const u32x4*)&wr2s[kk + j][4 * g];
                h2v a2 = as_h2(av[j]);
                h2v x2 = as_h2(xv[j]);
#if __has_builtin(__builtin_amdgcn_fdot2)
                o.x = __builtin_amdgcn_fdot2(a2, as_h2(wlv[0]), o.x, false);
                o.y = __builtin_amdgcn_fdot2(a2, as_h2(wlv[1]), o.y, false);
                o.z = __builtin_amdgcn_fdot2(a2, as_h2(wlv[2]), o.z, false);
                o.w = __builtin_amdgcn_fdot2(a2, as_h2(wlv[3]), o.w, false);
                o.x = __builtin_amdgcn_fdot2(x2, as_h2(wrv[0]), o.x, false);
                o.y = __builtin_amdgcn_fdot2(x2, as_h2(wrv[1]), o.y, false);
                o.z = __builtin_amdgcn_fdot2(x2, as_h2(wrv[2]), o.z, false);
                o.w = __builtin_amdgcn_fdot2(x2, as_h2(wrv[3]), o.w, false);
#else
                {
                    h2v l0 = as_h2(wlv[0]), l1 = as_h2(wlv[1]), l2 = as_h2(wlv[2]), l3 = as_h2(wlv[3]);
                    h2v q0 = as_h2(wrv[0]), q1 = as_h2(wrv[1]), q2 = as_h2(wrv[2]), q3 = as_h2(wrv[3]);
                    float b0 = (float)a2.x, b1 = (float)a2.y, x0 = (float)x2.x, x1 = (float)x2.y;
                    o.x += b0 * (float)l0.x + b1 * (float)l0.y + x0 * (float)q0.x + x1 * (float)q0.y;
                    o.y += b0 * (float)l1.x + b1 * (float)l1.y + x0 * (float)q1.x + x1 * (float)q1.y;
                    o.z += b0 * (float)l2.x + b1 * (float)l2.y + x0 * (float)q2.x + x1 * (float)q2.y;
                    o.w += b0 * (float)l3.x + b1 * (float)l3.y + x0 * (float)q3.x + x1 * (float)q3.y;
                }
#endif
            }
        }
        {
            h2v p0 = h2v{(_Float16)o.x, (_Float16)o.y};
            h2v p1 = h2v{(_Float16)o.z, (_Float16)o.w};
            u32x2 w;
            w.x = *(unsigned int*)&p0;
            w.y = *(unsigned int*)&p1;
            __builtin_nontemporal_store(w, (u32x2*)hp16 + (size_t)n * 16 + g);
        }

        float4 qv = make_float4(o.x * o.x, o.y * o.y, o.z * o.z, o.w * o.w);
#pragma unroll
        for (int m = 16; m <= 32; m <<= 1) {
            o.x += __shfl_xor(o.x, m); o.y += __shfl_xor(o.y, m);
            o.z += __shfl_xor(o.z, m); o.w += __shfl_xor(o.w, m);
            qv.x += __shfl_xor(qv.x, m); qv.y += __shfl_xor(qv.y, m);
            qv.z += __shfl_xor(qv.z, m); qv.w += __shfl_xor(qv.w, m);
        }
        if ((tid & 48) == 0) {
            atomicAdd(&ssum[4 * g + 0], o.x); atomicAdd(&ssum[4 * g + 1], o.y);
            atomicAdd(&ssum[4 * g + 2], o.z); atomicAdd(&ssum[4 * g + 3], o.w);
            atomicAdd(&ssq[4 * g + 0], qv.x);  atomicAdd(&ssq[4 * g + 1], qv.y);
            atomicAdd(&ssq[4 * g + 2], qv.z);  atomicAdd(&ssq[4 * g + 3], qv.w);
        }
        __syncthreads();   // protect tAh/tXh for next tile
    }
    if (tid < 64) {
        part[(2 * tid) * PBMAX + blockIdx.x]     = ssum[tid];
        part[(2 * tid + 1) * PBMAX + blockIdx.x] = ssq[tid];
    }
}

// ---------------- reduce partials -> BN scale/bias ----------------
__global__ void k_reduce_sb(const float* __restrict__ part, int PB,
                            const float* __restrict__ gamma, const float* __restrict__ beta,
                            float* __restrict__ sbv, int N) {
    int c = blockIdx.x;
    float s = 0.f, q = 0.f;
    for (int b = threadIdx.x; b < PB; b += 256) {
        s += part[(2 * c) * PBMAX + b];
        q += part[(2 * c + 1) * PBMAX + b];
    }
    __shared__ float rs[256], rq[256];
    rs[threadIdx.x] = s;
    rq[threadIdx.x] = q;
    __syncthreads();
    for (int off = 128; off > 0; off >>= 1) {
        if (threadIdx.x < off) {
            rs[threadIdx.x] += rs[threadIdx.x + off];
            rq[threadIdx.x] += rq[threadIdx.x + off];
        }
        __syncthreads();
    }
    if (threadIdx.x == 0) {
        float m = rs[0] / (float)N;
        float var = rq[0] / (float)N - m * m;
        float sc = gamma[c] * rsqrtf(var + BN_EPS);
        sbv[c]      = sc;
        sbv[64 + c] = beta[c] - m * sc;
    }
}

// ---------------- pool partials: 8 slices x 128 graphs, BN3+ReLU inline ----------------
__global__ void __launch_bounds__(256) k_pool_partial(
    const __half* __restrict__ hp16, const float* __restrict__ sbv,
    const int* __restrict__ batch, float* __restrict__ pooled_part, int N) {
    __shared__ float ssc[64], sbi[64];
    __shared__ float sm[256];
    if (threadIdx.x < 64) {
        ssc[threadIdx.x] = sbv[threadIdx.x];
        sbi[threadIdx.x] = sbv[64 + threadIdx.x];
    }
    __syncthreads();
    int gph = blockIdx.x >> 3;        // 128 graphs
    int slice = blockIdx.x & 7;       // 8 slices
    int lo = 0, hi = N;
    while (lo < hi) { int mid = (lo + hi) >> 1; if (batch[mid] < gph) lo = mid + 1; else hi = mid; }
    int start = lo;
    hi = N;
    while (lo < hi) { int mid = (lo + hi) >> 1; if (batch[mid] < gph + 1) lo = mid + 1; else hi = mid; }
    int end = lo;

    int c = threadIdx.x & 63, w = threadIdx.x >> 6;   // 4 walkers/block, 32 grid-wide/graph
    float s = 0.f;
    for (int r = start + slice * 4 + w; r < end; r += 32)
        s += fmaxf(__half2float(hp16[(size_t)r * 64 + c]) * ssc[c] + sbi[c], 0.f);
    sm[threadIdx.x] = s;
    __syncthreads();
    if (threadIdx.x < 64) {
        float t = sm[c] + sm[64 + c] + sm[128 + c] + sm[192 + c];
        pooled_part[(size_t)(gph * PSLICE + slice) * 64 + c] = t;
    }
}

// ---------------- head: fold slice partials + MLP ----------------
__global__ void __launch_bounds__(64) k_head(
    const float* __restrict__ pooled_part, const int* __restrict__ batch,
    const float* __restrict__ fc1w, const float* __restrict__ fc1b,
    const float* __restrict__ fc2w, const float* __restrict__ fc2b,
    float* __restrict__ out, int N) {
    __shared__ float pl[64], hid[64];
    int gph = blockIdx.x;
    int j = threadIdx.x;
    int lo = 0, hi = N;
    while (lo < hi) { int mid = (lo + hi) >> 1; if (batch[mid] < gph) lo = mid + 1; else hi = mid; }
    int start = lo;
    hi = N;
    while (lo < hi) { int mid = (lo + hi) >> 1; if (batch[mid] < gph + 1) lo = mid + 1; else hi = mid; }
    int cnt = lo - start;

    float t = 0.f;
#pragma unroll
    for (int s = 0; s < PSLICE; s++) t += pooled_part[(size_t)(gph * PSLICE + s) * 64 + j];
    pl[j] = t / fmaxf((float)cnt, 1.0f);
    __syncthreads();
    float v = fc1b[j];
    for (int k = 0; k < 64; k++) v += pl[k] * fc1w[j * 64 + k];
    hid[j] = fmaxf(v, 0.f);
    __syncthreads();
    if (j < 2) {
        float o = fc2b[j];
        for (int k = 0; k < 64; k++) o += hid[k] * fc2w[j * 64 + k];
        out[gph * 2 + j] = o;
    }
}

extern "C" void kernel_launch(void* const* d_in, const int* in_sizes, int n_in,
                              void* d_out, int out_size, void* d_ws, size_t ws_size,
                              hipStream_t stream) {
    const float* x    = (const float*)d_in[0];
    const int* ei     = (const int*)d_in[1];
    const int* batch  = (const int*)d_in[2];
    const float* w1l  = (const float*)d_in[3];
    const float* b1   = (const float*)d_in[4];
    const float* w1r  = (const float*)d_in[5];
    const float* bn1g = (const float*)d_in[6];
    const float* bn1b = (const float*)d_in[7];
    const float* w2l  = (const float*)d_in[8];
    const float* b2   = (const float*)d_in[9];
    const float* w2r  = (const float*)d_in[10];
    const float* bn2g = (const float*)d_in[11];
    const float* bn2b = (const float*)d_in[12];
    const float* w3l  = (const float*)d_in[13];
    const float* b3   = (const float*)d_in[14];
    const float* w3r  = (const float*)d_in[15];
    const float* bn3g = (const float*)d_in[16];
    const float* bn3b = (const float*)d_in[17];
    const float* fc1w = (const float*)d_in[18];
    const float* fc1b = (const float*)d_in[19];
    const float* fc2w = (const float*)d_in[20];
    const float* fc2b = (const float*)d_in[21];
    float* out = (float*)d_out;

    const int N = NN, E = NE;
    const int* srcp = ei;
    const int* dstp = ei + E;

    char* ws = (char*)d_ws;
    size_t off = 0;
    auto alloc = [&](size_t bytes) -> char* {
        char* p = ws + off;
        off += (bytes + 255) & ~(size_t)255;
        return p;
    };
    int* csr_src       = (int*)alloc(sizeof(int) * E);
    __half* hpA        = (__half*)alloc(sizeof(__half) * N * 64); // pre-BN fp16 ping
    __half* hpB        = (__half*)alloc(sizeof(__half) * N * 64); // pre-BN fp16 pong
    unsigned int* slab = (unsigned int*)alloc(sizeof(unsigned int) * (size_t)NBUK * BCAP);
    int* slab_cursor   = (int*)alloc(sizeof(int) * NBUK);
    int* row_ptr       = (int*)alloc(sizeof(int) * (N + 1));
    float* deg_inv     = (float*)alloc(sizeof(float) * N);
    float* part        = (float*)alloc(sizeof(float) * 128 * PBMAX);
    float* sbv         = (float*)alloc(sizeof(float) * 128);
    float* pooled_part = (float*)alloc(sizeof(float) * NG * PSLICE * 64);

    // slab (19.2 MB) is dead after k_bucket_csr -> reuse as activated buffer
    __half* hAct = (__half*)slab;

    hipMemsetAsync(slab_cursor, 0, sizeof(int) * NBUK, stream);

    // ---- CSR build + fused layer 1 -> hpA (pre-BN1) ----
    k_scatter<<<256, 512, 0, stream>>>(srcp, dstp, slab_cursor, slab, E);
    k_bucket_csr<<<NBUK, 512, 0, stream>>>(slab, slab_cursor, row_ptr, deg_inv,
                                           csr_src, x, w1l, b1, w1r, hpA, part);
    k_reduce_sb<<<64, 256, 0, stream>>>(part, NBUK, bn1g, bn1b, sbv, N);

    // layer 2: BN1+ReLU once per node, then gather/GEMM -> hpB (pre-BN2)
    k_bnact<<<1024, 256, 0, stream>>>(hpA, sbv, hAct);
    k_sage<<<GRID_SG, 512, 0, stream>>>(hAct, row_ptr, csr_src, deg_inv,
                                        w2l, b2, w2r, hpB, part);
    k_reduce_sb<<<64, 256, 0, stream>>>(part, GRID_SG, bn2g, bn2b, sbv, N);

    // layer 3: BN2+ReLU once per node, then gather/GEMM -> hpA (pre-BN3)
    k_bnact<<<1024, 256, 0, stream>>>(hpB, sbv, hAct);
    k_sage<<<GRID_SG, 512, 0, stream>>>(hAct, row_ptr, csr_src, deg_inv,
                                        w3l, b3, w3r, hpA, part);
    k_reduce_sb<<<64, 256, 0, stream>>>(part, GRID_SG, bn3g, bn3b, sbv, N);

    // pool (BN3+ReLU inline) + head
    k_pool_partial<<<NG * PSLICE, 256, 0, stream>>>(hpA, sbv, batch, pooled_part, N);
    k_head<<<NG, 64, 0, stream>>>(pooled_part, batch, fc1w, fc1b, fc2w, fc2b, out, N);
}